// Round 15
// baseline (1180.386 us; speedup 1.0000x reference)
//
#include <hip/hip_runtime.h>
#include <math.h>

#define NN 50000
#define EE 400000
#define EMBD 128
#define KIN 288
#define NITERS 2
#define EPSV 1e-5f
#define SAE 296      // pass0 A LDS stride (bf16 elems)
#define SA1 136      // pass1/node A LDS stride
#define NT_E 6250    // EE/64
#define G0P 512      // pass0 blocks per phase (1024 total = one co-resident round)
#define G1 1024

typedef __attribute__((ext_vector_type(8))) short bf16x8;
typedef __attribute__((ext_vector_type(4))) float f32x4;

#define MFMA16(a, b, c) __builtin_amdgcn_mfma_f32_16x16x32_bf16(a, b, c, 0, 0, 0)

__device__ __forceinline__ unsigned short f2bf(float x) {
  unsigned int u = __float_as_uint(x);
  u += 0x7fffu + ((u >> 16) & 1u);
  return (unsigned short)(u >> 16);
}

// swizzled 16B-chunk index: XOR low3 with row&7 (chunks <32 only)
__device__ __forceinline__ int physch(int ch, int row) {
  return (ch < 32) ? ((ch & ~7) | ((ch ^ (row & 7)) & 7)) : ch;
}

// ---------------- setup kernels ----------------

__global__ void k_zeroi(int* __restrict__ p, int n) {
  for (int i = blockIdx.x * blockDim.x + threadIdx.x; i < n;
       i += gridDim.x * blockDim.x)
    p[i] = 0;
}

__global__ void k_detect(const long long* __restrict__ e64, int* __restrict__ flag) {
  __shared__ int ok;
  if (threadIdx.x == 0) ok = 1;
  __syncthreads();
  for (int i = threadIdx.x; i < 4096; i += blockDim.x) {
    const long long v = e64[i];
    if (v < 0 || v >= NN) atomicAnd(&ok, 0);
  }
  __syncthreads();
  if (threadIdx.x == 0) *flag = ok;
}

__global__ void k_convert(const void* __restrict__ edges, const int* __restrict__ flag,
                          int* __restrict__ src, int* __restrict__ dst) {
  const int is64 = *flag;
  for (int i = blockIdx.x * blockDim.x + threadIdx.x; i < 2 * EE;
       i += gridDim.x * blockDim.x) {
    const int v = is64 ? (int)((const long long*)edges)[i] : ((const int*)edges)[i];
    if (i < EE) src[i] = v; else dst[i - EE] = v;
  }
}

__global__ void k_count(const int* __restrict__ src, const int* __restrict__ dst,
                        int* __restrict__ degp, int* __restrict__ degc) {
  for (int e = blockIdx.x * blockDim.x + threadIdx.x; e < EE;
       e += gridDim.x * blockDim.x) {
    atomicAdd(&degp[dst[e]], 1);
    atomicAdd(&degc[src[e]], 1);
  }
}

__global__ void k_dinv(const int* __restrict__ dp, const int* __restrict__ dc,
                       float* __restrict__ ip, float* __restrict__ ic) {
  for (int n = blockIdx.x * blockDim.x + threadIdx.x; n < NN;
       n += gridDim.x * blockDim.x) {
    ip[n] = dp[n] ? 1.f / (float)dp[n] : 0.f;
    ic[n] = dc[n] ? 1.f / (float)dc[n] : 0.f;
  }
}

// one-shot scan: 2 blocks x 1024 thr, 49 elems/thread serial + one 1024 LDS scan
__global__ __launch_bounds__(1024) void k_scan2(
    const int* __restrict__ degp, const int* __restrict__ degc,
    int* __restrict__ offp, int* __restrict__ offc) {
  const int* deg = blockIdx.x ? degc : degp;
  int* off = blockIdx.x ? offc : offp;
  __shared__ int sh[1024];
  const int t = threadIdx.x;
  const int i0 = t * 49;
  int s = 0;
#pragma unroll 1
  for (int k = 0; k < 49; ++k) {
    const int i = i0 + k;
    if (i < NN) s += deg[i];
  }
  sh[t] = s;
  __syncthreads();
  for (int o = 1; o < 1024; o <<= 1) {
    const int y = (t >= o) ? sh[t - o] : 0;
    __syncthreads();
    sh[t] += y;
    __syncthreads();
  }
  int base = sh[t] - s;  // exclusive prefix
#pragma unroll 1
  for (int k = 0; k < 49; ++k) {
    const int i = i0 + k;
    if (i < NN) {
      off[i] = base;
      base += deg[i];
    }
  }
  if (t == 1023) off[NN] = sh[1023];
}

__global__ void k_copycur(const int* __restrict__ offp, const int* __restrict__ offc,
                          int* __restrict__ curp, int* __restrict__ curc) {
  for (int i = blockIdx.x * blockDim.x + threadIdx.x; i < NN;
       i += gridDim.x * blockDim.x) {
    curp[i] = offp[i];
    curc[i] = offc[i];
  }
}

__global__ void k_scatter(const int* __restrict__ src, const int* __restrict__ dst,
                          int* __restrict__ curp, int* __restrict__ curc,
                          int* __restrict__ lstp, int* __restrict__ lstc) {
  for (int e = blockIdx.x * blockDim.x + threadIdx.x; e < EE;
       e += gridDim.x * blockDim.x) {
    const int pp = atomicAdd(&curp[dst[e]], 1);
    lstp[pp] = e;
    const int pc = atomicAdd(&curc[src[e]], 1);
    lstc[pc] = e;
  }
}

__global__ void k_initnodes(const float* __restrict__ in, float* __restrict__ nd,
                            unsigned short* __restrict__ xb) {
  const int tot = NN * EMBD / 4;
  for (int i = blockIdx.x * blockDim.x + threadIdx.x; i < tot;
       i += gridDim.x * blockDim.x) {
    const float4 v = ((const float4*)in)[i];
    ((float4*)nd)[i] = v;
    short4 b;
    b.x = (short)f2bf(v.x); b.y = (short)f2bf(v.y);
    b.z = (short)f2bf(v.z); b.w = (short)f2bf(v.w);
    *(short4*)&xb[(size_t)i * 4] = b;
  }
}

// W [K][128] f32 -> Wt [128][K] bf16
__global__ void k_prepW(const float* __restrict__ W, unsigned short* __restrict__ Wt,
                        int K) {
  const int idx = blockIdx.x * blockDim.x + threadIdx.x;
  if (idx < K * EMBD) {
    const int k = idx >> 7, n = idx & 127;
    Wt[(size_t)n * K + k] = f2bf(W[(size_t)k * EMBD + n]);
  }
}

// ea f32 [E][32] -> bf16
__global__ void k_prepea(const float* __restrict__ ea,
                         unsigned short* __restrict__ eab) {
  const int tot = EE * 32 / 8;
  for (int i = blockIdx.x * blockDim.x + threadIdx.x; i < tot;
       i += gridDim.x * blockDim.x) {
    const float4 a = ((const float4*)ea)[i * 2];
    const float4 b = ((const float4*)ea)[i * 2 + 1];
    union { unsigned short u[8]; uint4 v; } o;
    o.u[0] = f2bf(a.x); o.u[1] = f2bf(a.y); o.u[2] = f2bf(a.z); o.u[3] = f2bf(a.w);
    o.u[4] = f2bf(b.x); o.u[5] = f2bf(b.y); o.u[6] = f2bf(b.z); o.u[7] = f2bf(b.w);
    ((uint4*)eab)[i] = o.v;
  }
}

// ---------------- PASS0 merged: both phases, CSR order, 2-level reg prefetch ---
// Data regs hold CURRENT tile (staged instantly); index regs (e,i,j) hold
// tile+stride. During MFMA: issue next tile's DATA loads from known indices
// (no dependent chain) and refill index regs for tile+2*stride.

template <int EAB>
__global__ __launch_bounds__(256, 1) void k_pass0m(
    const unsigned short* __restrict__ xb,
    const int* __restrict__ l0, const int* __restrict__ i0,
    const int* __restrict__ j0, const unsigned short* __restrict__ W0,
    float* __restrict__ st0, unsigned short* __restrict__ Y0,
    const int* __restrict__ l1, const int* __restrict__ i1,
    const int* __restrict__ j1, const unsigned short* __restrict__ W1,
    float* __restrict__ st1, unsigned short* __restrict__ Y1,
    const float* __restrict__ ea, const unsigned short* __restrict__ eab,
    const int nb0) {
  __shared__ __align__(16) unsigned short Ab[64 * SAE];
  __shared__ float red[256];
  const int phase = (blockIdx.x >= nb0) ? 1 : 0;
  const int* __restrict__ lst = phase ? l1 : l0;
  const int* __restrict__ idx_i = phase ? i1 : i0;
  const int* __restrict__ idx_j = phase ? j1 : j0;
  const unsigned short* __restrict__ W1t = phase ? W1 : W0;
  float* __restrict__ stat = phase ? st1 : st0;
  unsigned short* __restrict__ Y = phase ? Y1 : Y0;
  const int stride = phase ? ((int)gridDim.x - nb0) : nb0;
  const int bl = blockIdx.x - phase * nb0;
  const int t = threadIdx.x;
  const int lane = t & 63, w = t >> 6, m = lane & 15, kg = lane >> 4;
  const int r = t >> 2, sub = t & 3;
  const int n0 = w * 32 + m, n1 = n0 + 16;
  bf16x8 B0[9], B1[9];
#pragma unroll
  for (int ks = 0; ks < 9; ++ks) {
    B0[ks] = *(const bf16x8*)&W1t[(size_t)n0 * KIN + ks * 32 + kg * 8];
    B1[ks] = *(const bf16x8*)&W1t[(size_t)n1 * KIN + ks * 32 + kg * 8];
  }
  float s0 = 0.f, s1 = 0.f, q0 = 0.f, q1 = 0.f;
  // XCD-chunk swizzle: bijective on [0,512) when stride==512, else identity
  int tile = (stride == 512) ? (((bl & 7) << 6) | (bl >> 3)) : bl;
  uint4 xreg[8];
  uint4 earg;
  {
    const int e = lst[tile * 64 + r];
    const int i = idx_i[e], j = idx_j[e];
    const uint4* xi = (const uint4*)(xb + (size_t)i * EMBD);
    const uint4* xj = (const uint4*)(xb + (size_t)j * EMBD);
#pragma unroll
    for (int qq = 0; qq < 8; ++qq) {
      const int c = sub + qq * 4;
      xreg[qq] = (c < 16) ? xi[c] : xj[c - 16];
    }
    if (EAB) {
      earg = *(const uint4*)&eab[(size_t)e * 32 + sub * 8];
    } else {
      const float4 e0 = *(const float4*)&ea[(size_t)e * 32 + sub * 8];
      const float4 e1 = *(const float4*)&ea[(size_t)e * 32 + sub * 8 + 4];
      union { unsigned short u[8]; uint4 v4; } o;
      o.u[0] = f2bf(e0.x); o.u[1] = f2bf(e0.y); o.u[2] = f2bf(e0.z);
      o.u[3] = f2bf(e0.w); o.u[4] = f2bf(e1.x); o.u[5] = f2bf(e1.y);
      o.u[6] = f2bf(e1.z); o.u[7] = f2bf(e1.w);
      earg = o.v4;
    }
  }
  // index regs for tile+stride
  int eA = 0, iA = 0, jA = 0;
  if (tile + stride < NT_E) {
    eA = lst[(tile + stride) * 64 + r];
    iA = idx_i[eA];
    jA = idx_j[eA];
  }
  while (tile < NT_E) {
    __syncthreads();  // Ab free (prev copy-out done)
    {
      unsigned short* rowp = &Ab[r * SAE];
#pragma unroll
      for (int qq = 0; qq < 8; ++qq) {
        const int c = sub + qq * 4;
        *(uint4*)&rowp[physch(c, r) * 8] = xreg[qq];
      }
      *(uint4*)&rowp[(32 + sub) * 8] = earg;
    }
    __syncthreads();
    const int next = tile + stride;
    if (next < NT_E) {
      // DATA loads for `next` from already-resident indices (no chain)
      const uint4* xi = (const uint4*)(xb + (size_t)iA * EMBD);
      const uint4* xj = (const uint4*)(xb + (size_t)jA * EMBD);
#pragma unroll
      for (int qq = 0; qq < 8; ++qq) {
        const int c = sub + qq * 4;
        xreg[qq] = (c < 16) ? xi[c] : xj[c - 16];
      }
      if (EAB) {
        earg = *(const uint4*)&eab[(size_t)eA * 32 + sub * 8];
      } else {
        const float4 e0 = *(const float4*)&ea[(size_t)eA * 32 + sub * 8];
        const float4 e1 = *(const float4*)&ea[(size_t)eA * 32 + sub * 8 + 4];
        union { unsigned short u[8]; uint4 v4; } o;
        o.u[0] = f2bf(e0.x); o.u[1] = f2bf(e0.y); o.u[2] = f2bf(e0.z);
        o.u[3] = f2bf(e0.w); o.u[4] = f2bf(e1.x); o.u[5] = f2bf(e1.y);
        o.u[6] = f2bf(e1.z); o.u[7] = f2bf(e1.w);
        earg = o.v4;
      }
      // INDEX refill for next+stride (2-level chain, needed a full phase later)
      if (next + stride < NT_E) {
        eA = lst[(next + stride) * 64 + r];
        iA = idx_i[eA];
        jA = idx_j[eA];
      }
    }
    const f32x4 zz = {0.f, 0.f, 0.f, 0.f};
    f32x4 acc[4][2] = {{zz, zz}, {zz, zz}, {zz, zz}, {zz, zz}};
#pragma unroll
    for (int ks = 0; ks < 9; ++ks) {
      const int aoff = physch(ks * 4 + kg, m) * 8;
#pragma unroll
      for (int mt = 0; mt < 4; ++mt) {
        const bf16x8 a = *(const bf16x8*)&Ab[(mt * 16 + m) * SAE + aoff];
        acc[mt][0] = MFMA16(a, B0[ks], acc[mt][0]);
        acc[mt][1] = MFMA16(a, B1[ks], acc[mt][1]);
      }
    }
#pragma unroll
    for (int mt = 0; mt < 4; ++mt)
#pragma unroll
      for (int r2 = 0; r2 < 4; ++r2) {
        const float v0 = acc[mt][0][r2], v1 = acc[mt][1][r2];
        s0 += v0; q0 += v0 * v0;
        s1 += v1; q1 += v1 * v1;
      }
    __syncthreads();  // all waves done reading Ab
#pragma unroll
    for (int nt = 0; nt < 2; ++nt) {
      const int c = w * 32 + nt * 16 + m;
      const int cc = c >> 3, cl = c & 7;
#pragma unroll
      for (int mt = 0; mt < 4; ++mt)
#pragma unroll
        for (int r2 = 0; r2 < 4; ++r2) {
          const int rw = mt * 16 + kg * 4 + r2;
          Ab[rw * SAE + physch(cc, rw) * 8 + cl] = f2bf(acc[mt][nt][r2]);
        }
    }
    __syncthreads();
    // coalesced writeout: 4 insts x 1KB contiguous per wave (CSR-position order)
    unsigned short* Yt = Y + (size_t)tile * 64 * EMBD;
#pragma unroll
    for (int i = 0; i < 4; ++i) {
      const int g = i * 2048 + t * 8;
      const int row = g >> 7, ch = (g >> 3) & 15;
      *(uint4*)&Yt[g] = *(const uint4*)&Ab[row * SAE + physch(ch, row) * 8];
    }
    tile = next;
  }
  s0 += __shfl_xor(s0, 16); s0 += __shfl_xor(s0, 32);
  q0 += __shfl_xor(q0, 16); q0 += __shfl_xor(q0, 32);
  s1 += __shfl_xor(s1, 16); s1 += __shfl_xor(s1, 32);
  q1 += __shfl_xor(q1, 16); q1 += __shfl_xor(q1, 32);
  if (kg == 0) {
    const int c0 = w * 32 + m, c1 = c0 + 16;
    red[c0] = s0; red[128 + c0] = q0;
    red[c1] = s1; red[128 + c1] = q1;
  }
  __syncthreads();
  if (t < 128) {
    atomicAdd(&stat[t], red[t]);
    atomicAdd(&stat[128 + t], red[128 + t]);
  }
}

// ---------------- PASS1 body: BN1+ReLU -> GEMM2 -> stats2 + Y2 over Y1 ----------

__device__ __forceinline__ void pass1_body(
    const unsigned short* __restrict__ W2t, float* __restrict__ stat,
    unsigned short* __restrict__ Y, int tile, const int stride) {
  __shared__ __align__(16) unsigned short Ab[64 * SA1];
  __shared__ float red[256];
  const int t = threadIdx.x;
  const int lane = t & 63, w = t >> 6, m = lane & 15, kg = lane >> 4;
  const int n0 = w * 32 + m, n1 = n0 + 16;
  const int ch = t & 15;
  bf16x8 B0[4], B1[4];
#pragma unroll
  for (int ks = 0; ks < 4; ++ks) {
    B0[ks] = *(const bf16x8*)&W2t[(size_t)n0 * EMBD + ks * 32 + kg * 8];
    B1[ks] = *(const bf16x8*)&W2t[(size_t)n1 * EMBD + ks * 32 + kg * 8];
  }
  float scr[8], shr[8];
#pragma unroll
  for (int h = 0; h < 8; ++h) {
    scr[h] = stat[256 + ch * 8 + h];
    shr[h] = stat[384 + ch * 8 + h];
  }
  float s0 = 0.f, s1 = 0.f, q0 = 0.f, q1 = 0.f;
  uint4 yreg[4];
  {
    const unsigned short* Yt = Y + (size_t)tile * 64 * EMBD;
#pragma unroll
    for (int i = 0; i < 4; ++i)
      yreg[i] = *(const uint4*)&Yt[i * 2048 + t * 8];
  }
  while (tile < NT_E) {
    __syncthreads();
#pragma unroll
    for (int i = 0; i < 4; ++i) {
      const int row = i * 16 + (t >> 4);
      const unsigned int* pv = (const unsigned int*)&yreg[i];
      union { unsigned short u[8]; uint4 v; } o;
#pragma unroll
      for (int h = 0; h < 4; ++h) {
        const unsigned int pw = pv[h];
        const float f0 = __uint_as_float(pw << 16);
        const float f1 = __uint_as_float(pw & 0xffff0000u);
        o.u[h * 2] = f2bf(fmaxf(fmaf(f0, scr[h * 2], shr[h * 2]), 0.f));
        o.u[h * 2 + 1] = f2bf(fmaxf(fmaf(f1, scr[h * 2 + 1], shr[h * 2 + 1]), 0.f));
      }
      *(uint4*)&Ab[row * SA1 + physch(ch, row) * 8] = o.v;
    }
    __syncthreads();
    const int next = tile + stride;
    if (next < NT_E) {
      const unsigned short* Yt = Y + (size_t)next * 64 * EMBD;
#pragma unroll
      for (int i = 0; i < 4; ++i)
        yreg[i] = *(const uint4*)&Yt[i * 2048 + t * 8];
    }
    const f32x4 zz = {0.f, 0.f, 0.f, 0.f};
    f32x4 acc[4][2] = {{zz, zz}, {zz, zz}, {zz, zz}, {zz, zz}};
#pragma unroll
    for (int ks = 0; ks < 4; ++ks) {
      const int aoff = physch(ks * 4 + kg, m) * 8;
#pragma unroll
      for (int mt = 0; mt < 4; ++mt) {
        const bf16x8 a = *(const bf16x8*)&Ab[(mt * 16 + m) * SA1 + aoff];
        acc[mt][0] = MFMA16(a, B0[ks], acc[mt][0]);
        acc[mt][1] = MFMA16(a, B1[ks], acc[mt][1]);
      }
    }
#pragma unroll
    for (int mt = 0; mt < 4; ++mt)
#pragma unroll
      for (int r2 = 0; r2 < 4; ++r2) {
        const float v0 = acc[mt][0][r2], v1 = acc[mt][1][r2];
        s0 += v0; q0 += v0 * v0;
        s1 += v1; q1 += v1 * v1;
      }
    __syncthreads();
#pragma unroll
    for (int nt = 0; nt < 2; ++nt) {
      const int c = w * 32 + nt * 16 + m;
      const int cc = c >> 3, cl = c & 7;
#pragma unroll
      for (int mt = 0; mt < 4; ++mt)
#pragma unroll
        for (int r2 = 0; r2 < 4; ++r2) {
          const int rw = mt * 16 + kg * 4 + r2;
          Ab[rw * SA1 + physch(cc, rw) * 8 + cl] = f2bf(acc[mt][nt][r2]);
        }
    }
    __syncthreads();
    unsigned short* Yo = Y + (size_t)tile * 64 * EMBD;
#pragma unroll
    for (int i = 0; i < 4; ++i) {
      const int g = i * 2048 + t * 8;
      const int row = g >> 7, c2 = (g >> 3) & 15;
      *(uint4*)&Yo[g] = *(const uint4*)&Ab[row * SA1 + physch(c2, row) * 8];
    }
    tile = next;
  }
  s0 += __shfl_xor(s0, 16); s0 += __shfl_xor(s0, 32);
  q0 += __shfl_xor(q0, 16); q0 += __shfl_xor(q0, 32);
  s1 += __shfl_xor(s1, 16); s1 += __shfl_xor(s1, 32);
  q1 += __shfl_xor(q1, 16); q1 += __shfl_xor(q1, 32);
  if (kg == 0) {
    const int c0 = w * 32 + m, c1 = c0 + 16;
    red[c0] = s0; red[128 + c0] = q0;
    red[c1] = s1; red[128 + c1] = q1;
  }
  __syncthreads();
  if (t < 128) {
    atomicAdd(&stat[512 + t], red[t]);
    atomicAdd(&stat[640 + t], red[128 + t]);
  }
}

__global__ __launch_bounds__(256, 3) void k_pass1(
    const unsigned short* __restrict__ W2t, float* __restrict__ stat,
    unsigned short* __restrict__ Y) {
  pass1_body(W2t, stat, Y, blockIdx.x, G1);
}

__global__ __launch_bounds__(256, 3) void k_pass1m(
    const unsigned short* __restrict__ Wp, const unsigned short* __restrict__ Wc,
    float* __restrict__ statP, float* __restrict__ statC,
    unsigned short* __restrict__ Yp, unsigned short* __restrict__ Yc) {
  const int phase = (blockIdx.x >= G1) ? 1 : 0;
  const unsigned short* W2t = phase ? Wc : Wp;
  float* stat = phase ? statC : statP;
  unsigned short* Y = phase ? Yc : Yp;
  pass1_body(W2t, stat, Y, blockIdx.x - phase * G1, G1);
}

// ---------------- PASS2 merged: Y in CSR order -> SEQUENTIAL reads ------------

__global__ __launch_bounds__(256) void k_aggm(
    const unsigned short* __restrict__ Yp, const unsigned short* __restrict__ Yc,
    const int* __restrict__ offp, const int* __restrict__ offc,
    const float* __restrict__ statP, const float* __restrict__ statC,
    const float* __restrict__ dinvp, const float* __restrict__ dinvc,
    float* __restrict__ agg) {
  const int n = blockIdx.x * 4 + (threadIdx.x >> 6);
  const int lane = threadIdx.x & 63;
  if (n >= NN) return;
  float r0, r1;
  {
    const int o0 = offp[n], o1 = offp[n + 1];
    const float sc0 = statP[768 + 2 * lane], sc1 = statP[768 + 2 * lane + 1];
    const float sh0 = statP[896 + 2 * lane], sh1 = statP[896 + 2 * lane + 1];
    float a0 = 0.f, a1 = 0.f;
    for (int o = o0; o < o1; ++o) {
      const unsigned int pw = ((const unsigned int*)(Yp + (size_t)o * EMBD))[lane];
      a0 += fmaxf(fmaf(__uint_as_float(pw << 16), sc0, sh0), 0.f);
      a1 += fmaxf(fmaf(__uint_as_float(pw & 0xffff0000u), sc1, sh1), 0.f);
    }
    const float d = dinvp[n];
    r0 = a0 * d;
    r1 = a1 * d;
  }
  {
    const int o0 = offc[n], o1 = offc[n + 1];
    const float sc0 = statC[768 + 2 * lane], sc1 = statC[768 + 2 * lane + 1];
    const float sh0 = statC[896 + 2 * lane], sh1 = statC[896 + 2 * lane + 1];
    float a0 = 0.f, a1 = 0.f;
    for (int o = o0; o < o1; ++o) {
      const unsigned int pw = ((const unsigned int*)(Yc + (size_t)o * EMBD))[lane];
      a0 += fmaxf(fmaf(__uint_as_float(pw << 16), sc0, sh0), 0.f);
      a1 += fmaxf(fmaf(__uint_as_float(pw & 0xffff0000u), sc1, sh1), 0.f);
    }
    const float d = dinvc[n];
    r0 += a0 * d;
    r1 += a1 * d;
  }
  float2 out;
  out.x = r0;
  out.y = r1;
  ((float2*)(agg + (size_t)n * EMBD))[lane] = out;
}

template <int ADD>
__global__ __launch_bounds__(256) void k_agg2(
    const unsigned short* __restrict__ Y2, const int* __restrict__ off,
    const float* __restrict__ stat, const float* __restrict__ dinv,
    float* __restrict__ agg) {
  const int n = blockIdx.x * 4 + (threadIdx.x >> 6);
  const int lane = threadIdx.x & 63;
  if (n >= NN) return;
  const int o0 = off[n], o1 = off[n + 1];
  const float sc0 = stat[768 + 2 * lane], sc1 = stat[768 + 2 * lane + 1];
  const float sh0 = stat[896 + 2 * lane], sh1 = stat[896 + 2 * lane + 1];
  float a0 = 0.f, a1 = 0.f;
  for (int o = o0; o < o1; ++o) {
    const unsigned int pw = ((const unsigned int*)(Y2 + (size_t)o * EMBD))[lane];
    a0 += fmaxf(fmaf(__uint_as_float(pw << 16), sc0, sh0), 0.f);
    a1 += fmaxf(fmaf(__uint_as_float(pw & 0xffff0000u), sc1, sh1), 0.f);
  }
  const float d = dinv[n];
  float2 out;
  if (ADD) {
    const float2 prev = ((const float2*)(agg + (size_t)n * EMBD))[lane];
    out.x = prev.x + a0 * d;
    out.y = prev.y + a1 * d;
  } else {
    out.x = a0 * d;
    out.y = a1 * d;
  }
  ((float2*)(agg + (size_t)n * EMBD))[lane] = out;
}

// ---------------- node update GEMM ----------------

template <int NK, bool SWZ>
__device__ __forceinline__ void gemm_g(const unsigned short* Ab, const int sa,
                                       const unsigned short* __restrict__ Wt,
                                       const int K, const int m, const int kg,
                                       const int w, f32x4 acc[4][2]) {
  const int n0 = w * 32 + m, n1 = n0 + 16;
#pragma unroll
  for (int ks = 0; ks < NK; ++ks) {
    const int koff = ks * 32 + kg * 8;
    const int aoff = SWZ ? physch(koff >> 3, m) * 8 : koff;
    const bf16x8 b0 = *(const bf16x8*)&Wt[(size_t)n0 * K + koff];
    const bf16x8 b1 = *(const bf16x8*)&Wt[(size_t)n1 * K + koff];
#pragma unroll
    for (int mt = 0; mt < 4; ++mt) {
      const bf16x8 a = *(const bf16x8*)&Ab[(mt * 16 + m) * sa + aoff];
      acc[mt][0] = MFMA16(a, b0, acc[mt][0]);
      acc[mt][1] = MFMA16(a, b1, acc[mt][1]);
    }
  }
}

__device__ __forceinline__ void stats_epi64(const f32x4 acc[4][2], float* red,
                                            float* __restrict__ statg, const int t,
                                            const int m, const int kg, const int w) {
#pragma unroll
  for (int nt = 0; nt < 2; ++nt) {
    float s = 0.f, q = 0.f;
#pragma unroll
    for (int mt = 0; mt < 4; ++mt)
#pragma unroll
      for (int r = 0; r < 4; ++r) {
        const float v = acc[mt][nt][r];
        s += v;
        q += v * v;
      }
    s += __shfl_xor(s, 16); s += __shfl_xor(s, 32);
    q += __shfl_xor(q, 16); q += __shfl_xor(q, 32);
    if (kg == 0) {
      const int c = w * 32 + nt * 16 + m;
      red[c] = s;
      red[128 + c] = q;
    }
  }
  __syncthreads();
  if (t < 128) {
    atomicAdd(&statg[t], red[t]);
    atomicAdd(&statg[128 + t], red[128 + t]);
  }
}

__global__ __launch_bounds__(256) void k_node(
    const float* __restrict__ nd, float* __restrict__ ag,
    const unsigned short* __restrict__ Wt, float* __restrict__ stat) {
  __shared__ __align__(16) unsigned short Ab[64 * SA1];
  __shared__ float red[256];
  const int t = threadIdx.x;
  const int n0 = blockIdx.x * 64;
  {
    const int r = t >> 2, sub = t & 3;
    const int row = n0 + r;
    unsigned short* drow = &Ab[r * SA1];
#pragma unroll
    for (int q = 0; q < 8; ++q) {
      const int c4 = sub + q * 4;
      float4 va;
      if (row < NN) {
        va = ((const float4*)(nd + (size_t)row * EMBD))[c4];
        const float4 vb = ((const float4*)(ag + (size_t)row * EMBD))[c4];
        va.x += vb.x; va.y += vb.y; va.z += vb.z; va.w += vb.w;
      } else {
        va.x = va.y = va.z = va.w = 0.f;
      }
      short4 b;
      b.x = (short)f2bf(va.x); b.y = (short)f2bf(va.y);
      b.z = (short)f2bf(va.z); b.w = (short)f2bf(va.w);
      *(short4*)&drow[c4 * 4] = b;
    }
  }
  __syncthreads();
  const int lane = t & 63, w = t >> 6, m = lane & 15, kg = lane >> 4;
  const f32x4 zz = {0.f, 0.f, 0.f, 0.f};
  f32x4 acc[4][2] = {{zz, zz}, {zz, zz}, {zz, zz}, {zz, zz}};
  gemm_g<4, false>(Ab, SA1, Wt, EMBD, m, kg, w, acc);
#pragma unroll
  for (int nt = 0; nt < 2; ++nt) {
    const int c = w * 32 + nt * 16 + m;
#pragma unroll
    for (int mt = 0; mt < 4; ++mt)
#pragma unroll
      for (int r = 0; r < 4; ++r) {
        const int row = n0 + mt * 16 + kg * 4 + r;
        if (row < NN) ag[(size_t)row * EMBD + c] = acc[mt][nt][r];
      }
  }
  stats_epi64(acc, red, stat, t, m, kg, w);
}

// ---------------- BN finalize / node residual ----------------

__device__ __forceinline__ void finalize_one(float* __restrict__ sb,
                                             const float* __restrict__ g,
                                             const float* __restrict__ be,
                                             float cnt, int c) {
  const float s = sb[c], sq = sb[EMBD + c];
  const float m = s / cnt;
  float v = sq / cnt - m * m;
  v = fmaxf(v, 0.f);
  const float rs = rsqrtf(v + EPSV);
  const float sc = g[c] * rs;
  sb[256 + c] = sc;
  sb[384 + c] = be[c] - m * sc;
  sb[c] = 0.f;
  sb[EMBD + c] = 0.f;
}

__global__ void k_finalize(float* __restrict__ statbase, const float* __restrict__ g,
                           const float* __restrict__ be, float cnt) {
  const int t = threadIdx.x;
  if (t < EMBD) finalize_one(statbase, g, be, cnt, t);
}

__global__ void k_finalize2(float* __restrict__ sA, const float* __restrict__ gA,
                            const float* __restrict__ bA, float* __restrict__ sB,
                            const float* __restrict__ gB, const float* __restrict__ bB,
                            float cnt) {
  const int t = threadIdx.x;
  if (t < EMBD) finalize_one(sA, gA, bA, cnt, t);
  else finalize_one(sB, gB, bB, cnt, t - EMBD);
}

__global__ void k_update(float* __restrict__ nd, unsigned short* __restrict__ xb,
                         const float* __restrict__ Z, const float* __restrict__ stat) {
  const float* sc = stat + 256;
  const float* sh = stat + 384;
  const int total = NN * EMBD / 4;
  for (int i = blockIdx.x * blockDim.x + threadIdx.x; i < total;
       i += gridDim.x * blockDim.x) {
    const int c4 = i & 31;
    const float4 v = ((const float4*)Z)[i];
    const float4 s4 = ((const float4*)sc)[c4];
    const float4 h4 = ((const float4*)sh)[c4];
    float4 nv = ((float4*)nd)[i];
    nv.x += fmaxf(fmaf(v.x, s4.x, h4.x), 0.f);
    nv.y += fmaxf(fmaf(v.y, s4.y, h4.y), 0.f);
    nv.z += fmaxf(fmaf(v.z, s4.z, h4.z), 0.f);
    nv.w += fmaxf(fmaf(v.w, s4.w, h4.w), 0.f);
    ((float4*)nd)[i] = nv;
    short4 b;
    b.x = (short)f2bf(nv.x); b.y = (short)f2bf(nv.y);
    b.z = (short)f2bf(nv.z); b.w = (short)f2bf(nv.w);
    *(short4*)&xb[(size_t)i * 4] = b;
  }
}

// ---------------- launch ----------------

extern "C" void kernel_launch(void* const* d_in, const int* in_sizes, int n_in,
                              void* d_out, int out_size, void* d_ws, size_t ws_size,
                              hipStream_t stream) {
  const float* in_nodes = (const float*)d_in[0];
  const void* edges = d_in[1];
  const float* ea = (const float*)d_in[2];
  const float* fW = (const float*)d_in[3];
  const float* fg = (const float*)d_in[5];
  const float* fbe = (const float*)d_in[6];
  const float* p_[8];
  const float* c_[8];
  for (int i = 0; i < 8; ++i) {
    p_[i] = (const float*)d_in[7 + i];
    c_[i] = (const float*)d_in[15 + i];
  }
  float* nodes = (float*)d_out;

  char* base = (char*)d_ws;
  size_t cur = 0;
  auto take = [&](size_t bytes) -> void* {
    void* p = base + cur;
    cur = (cur + bytes + 255) & ~(size_t)255;
    return p;
  };
  float* agg = (float*)take((size_t)NN * EMBD * 4);
  unsigned short* xb = (unsigned short*)take((size_t)NN * EMBD * 2);
  int* src = (int*)take(EE * 4);
  int* dst = (int*)take(EE * 4);
  int* lstp = (int*)take(EE * 4);
  int* lstc = (int*)take(EE * 4);
  int* offp = (int*)take((NN + 1) * 4);
  int* offc = (int*)take((NN + 1) * 4);
  int* curp = (int*)take(NN * 4);
  int* curc = (int*)take(NN * 4);
  float* dinvp = (float*)take(NN * 4);
  float* dinvc = (float*)take(NN * 4);
  float* stat = (float*)take(2048 * 4);
  int* flag = (int*)take(4);
  unsigned short* pW1t = (unsigned short*)take((size_t)EMBD * KIN * 2);
  unsigned short* pW2t = (unsigned short*)take((size_t)EMBD * EMBD * 2);
  unsigned short* cW1t = (unsigned short*)take((size_t)EMBD * KIN * 2);
  unsigned short* cW2t = (unsigned short*)take((size_t)EMBD * EMBD * 2);
  unsigned short* fWt = (unsigned short*)take((size_t)EMBD * EMBD * 2);
  unsigned short* Y1p = (unsigned short*)take((size_t)EE * EMBD * 2);  // 102.4 MB
  const size_t y_bytes = (size_t)EE * EMBD * 2;
  const bool useM = (cur + y_bytes) <= ws_size;   // merged path needs Y1c
  unsigned short* Y1c = useM ? (unsigned short*)take(y_bytes) : nullptr;
  const size_t eab_bytes = (size_t)EE * 32 * 2;
  const bool useEab = (cur + eab_bytes) <= ws_size;
  unsigned short* eab = useEab ? (unsigned short*)take(eab_bytes) : nullptr;

  k_zeroi<<<64, 256, 0, stream>>>((int*)stat, 2048);
  k_zeroi<<<128, 256, 0, stream>>>(curp, NN);
  k_zeroi<<<128, 256, 0, stream>>>(curc, NN);
  k_detect<<<1, 256, 0, stream>>>((const long long*)edges, flag);
  k_convert<<<1024, 256, 0, stream>>>(edges, flag, src, dst);
  k_count<<<1024, 256, 0, stream>>>(src, dst, curp, curc);
  k_dinv<<<128, 256, 0, stream>>>(curp, curc, dinvp, dinvc);
  k_scan2<<<2, 1024, 0, stream>>>(curp, curc, offp, offc);
  k_copycur<<<128, 256, 0, stream>>>(offp, offc, curp, curc);
  k_scatter<<<1024, 256, 0, stream>>>(src, dst, curp, curc, lstp, lstc);
  k_initnodes<<<2048, 256, 0, stream>>>(in_nodes, nodes, xb);
  k_prepW<<<(KIN * EMBD + 255) / 256, 256, 0, stream>>>(p_[0], pW1t, KIN);
  k_prepW<<<(EMBD * EMBD + 255) / 256, 256, 0, stream>>>(p_[4], pW2t, EMBD);
  k_prepW<<<(KIN * EMBD + 255) / 256, 256, 0, stream>>>(c_[0], cW1t, KIN);
  k_prepW<<<(EMBD * EMBD + 255) / 256, 256, 0, stream>>>(c_[4], cW2t, EMBD);
  k_prepW<<<(EMBD * EMBD + 255) / 256, 256, 0, stream>>>(fW, fWt, EMBD);
  if (useEab) k_prepea<<<2048, 256, 0, stream>>>(ea, eab);

  const int NB = (NN + 63) / 64;  // 782
  float* statP = stat;
  float* statC = stat + 1024;

  for (int it = 0; it < NITERS; ++it) {
    if (useM) {
      if (useEab)
        k_pass0m<1><<<2 * G0P, 256, 0, stream>>>(
            xb, lstp, dst, src, pW1t, statP, Y1p,
            lstc, src, dst, cW1t, statC, Y1c, ea, eab, G0P);
      else
        k_pass0m<0><<<2 * G0P, 256, 0, stream>>>(
            xb, lstp, dst, src, pW1t, statP, Y1p,
            lstc, src, dst, cW1t, statC, Y1c, ea, eab, G0P);
      k_finalize2<<<1, 256, 0, stream>>>(statP, p_[2], p_[3],
                                         statC, c_[2], c_[3], (float)EE);
      k_pass1m<<<2 * G1, 256, 0, stream>>>(pW2t, cW2t, statP, statC, Y1p, Y1c);
      k_finalize2<<<1, 256, 0, stream>>>(statP + 512, p_[6], p_[7],
                                         statC + 512, c_[6], c_[7], (float)EE);
      k_aggm<<<NN / 4, 256, 0, stream>>>(Y1p, Y1c, offp, offc,
                                         statP, statC, dinvp, dinvc, agg);
    } else {
      k_pass0m<0><<<G0P, 256, 0, stream>>>(
          xb, lstp, dst, src, pW1t, statP, Y1p,
          lstp, dst, src, pW1t, statP, Y1p, ea, eab, G0P);
      k_finalize<<<1, 128, 0, stream>>>(statP, p_[2], p_[3], (float)EE);
      k_pass1<<<G1, 256, 0, stream>>>(pW2t, statP, Y1p);
      k_finalize<<<1, 128, 0, stream>>>(statP + 512, p_[6], p_[7], (float)EE);
      k_agg2<0><<<NN / 4, 256, 0, stream>>>(Y1p, offp, statP, dinvp, agg);
      k_pass0m<0><<<G0P, 256, 0, stream>>>(
          xb, lstc, src, dst, cW1t, statP, Y1p,
          lstc, src, dst, cW1t, statP, Y1p, ea, eab, G0P);
      k_finalize<<<1, 128, 0, stream>>>(statP, c_[2], c_[3], (float)EE);
      k_pass1<<<G1, 256, 0, stream>>>(cW2t, statP, Y1p);
      k_finalize<<<1, 128, 0, stream>>>(statP + 512, c_[6], c_[7], (float)EE);
      k_agg2<1><<<NN / 4, 256, 0, stream>>>(Y1p, offc, statP, dinvc, agg);
    }
    // node update
    k_node<<<NB, 256, 0, stream>>>(nodes, agg, fWt, statP);
    k_finalize<<<1, 128, 0, stream>>>(statP, fg, fbe, (float)NN);
    k_update<<<2048, 256, 0, stream>>>(nodes, xb, agg, statP);
  }
}

// Round 16
// 920.222 us; speedup vs baseline: 1.2827x; 1.2827x over previous
//
#include <hip/hip_runtime.h>
#include <math.h>

#define NN 50000
#define EE 400000
#define EMBD 128
#define KIN 288
#define NITERS 2
#define EPSV 1e-5f
#define SAE 296      // pass0 A LDS stride (bf16 elems)
#define SA1 136      // pass1/node A LDS stride
#define NT_E 6250    // EE/64
#define G0P 512      // pass0 blocks per phase (1024 total = one co-resident round)
#define G1 1024

typedef __attribute__((ext_vector_type(8))) short bf16x8;
typedef __attribute__((ext_vector_type(4))) float f32x4;

#define MFMA16(a, b, c) __builtin_amdgcn_mfma_f32_16x16x32_bf16(a, b, c, 0, 0, 0)

__device__ __forceinline__ unsigned short f2bf(float x) {
  unsigned int u = __float_as_uint(x);
  u += 0x7fffu + ((u >> 16) & 1u);
  return (unsigned short)(u >> 16);
}

// swizzled 16B-chunk index: XOR low3 with row&7 (chunks <32 only)
__device__ __forceinline__ int physch(int ch, int row) {
  return (ch < 32) ? ((ch & ~7) | ((ch ^ (row & 7)) & 7)) : ch;
}

// ---------------- setup kernels ----------------

__global__ void k_zeroi(int* __restrict__ p, int n) {
  for (int i = blockIdx.x * blockDim.x + threadIdx.x; i < n;
       i += gridDim.x * blockDim.x)
    p[i] = 0;
}

__global__ void k_detect(const long long* __restrict__ e64, int* __restrict__ flag) {
  __shared__ int ok;
  if (threadIdx.x == 0) ok = 1;
  __syncthreads();
  for (int i = threadIdx.x; i < 4096; i += blockDim.x) {
    const long long v = e64[i];
    if (v < 0 || v >= NN) atomicAnd(&ok, 0);
  }
  __syncthreads();
  if (threadIdx.x == 0) *flag = ok;
}

__global__ void k_convert(const void* __restrict__ edges, const int* __restrict__ flag,
                          int* __restrict__ src, int* __restrict__ dst) {
  const int is64 = *flag;
  for (int i = blockIdx.x * blockDim.x + threadIdx.x; i < 2 * EE;
       i += gridDim.x * blockDim.x) {
    const int v = is64 ? (int)((const long long*)edges)[i] : ((const int*)edges)[i];
    if (i < EE) src[i] = v; else dst[i - EE] = v;
  }
}

__global__ void k_count(const int* __restrict__ src, const int* __restrict__ dst,
                        int* __restrict__ degp, int* __restrict__ degc) {
  for (int e = blockIdx.x * blockDim.x + threadIdx.x; e < EE;
       e += gridDim.x * blockDim.x) {
    atomicAdd(&degp[dst[e]], 1);
    atomicAdd(&degc[src[e]], 1);
  }
}

__global__ void k_dinv(const int* __restrict__ dp, const int* __restrict__ dc,
                       float* __restrict__ ip, float* __restrict__ ic) {
  for (int n = blockIdx.x * blockDim.x + threadIdx.x; n < NN;
       n += gridDim.x * blockDim.x) {
    ip[n] = dp[n] ? 1.f / (float)dp[n] : 0.f;
    ic[n] = dc[n] ? 1.f / (float)dc[n] : 0.f;
  }
}

// one-shot scan: 2 blocks x 1024 thr, 49 elems/thread serial + one 1024 LDS scan
__global__ __launch_bounds__(1024) void k_scan2(
    const int* __restrict__ degp, const int* __restrict__ degc,
    int* __restrict__ offp, int* __restrict__ offc) {
  const int* deg = blockIdx.x ? degc : degp;
  int* off = blockIdx.x ? offc : offp;
  __shared__ int sh[1024];
  const int t = threadIdx.x;
  const int i0 = t * 49;
  int s = 0;
#pragma unroll 1
  for (int k = 0; k < 49; ++k) {
    const int i = i0 + k;
    if (i < NN) s += deg[i];
  }
  sh[t] = s;
  __syncthreads();
  for (int o = 1; o < 1024; o <<= 1) {
    const int y = (t >= o) ? sh[t - o] : 0;
    __syncthreads();
    sh[t] += y;
    __syncthreads();
  }
  int base = sh[t] - s;  // exclusive prefix
#pragma unroll 1
  for (int k = 0; k < 49; ++k) {
    const int i = i0 + k;
    if (i < NN) {
      off[i] = base;
      base += deg[i];
    }
  }
  if (t == 1023) off[NN] = sh[1023];
}

__global__ void k_copycur(const int* __restrict__ offp, const int* __restrict__ offc,
                          int* __restrict__ curp, int* __restrict__ curc) {
  for (int i = blockIdx.x * blockDim.x + threadIdx.x; i < NN;
       i += gridDim.x * blockDim.x) {
    curp[i] = offp[i];
    curc[i] = offc[i];
  }
}

__global__ void k_scatter(const int* __restrict__ src, const int* __restrict__ dst,
                          int* __restrict__ curp, int* __restrict__ curc,
                          int* __restrict__ lstp, int* __restrict__ lstc) {
  for (int e = blockIdx.x * blockDim.x + threadIdx.x; e < EE;
       e += gridDim.x * blockDim.x) {
    const int pp = atomicAdd(&curp[dst[e]], 1);
    lstp[pp] = e;
    const int pc = atomicAdd(&curc[src[e]], 1);
    lstc[pc] = e;
  }
}

__global__ void k_initnodes(const float* __restrict__ in, float* __restrict__ nd,
                            unsigned short* __restrict__ xb) {
  const int tot = NN * EMBD / 4;
  for (int i = blockIdx.x * blockDim.x + threadIdx.x; i < tot;
       i += gridDim.x * blockDim.x) {
    const float4 v = ((const float4*)in)[i];
    ((float4*)nd)[i] = v;
    short4 b;
    b.x = (short)f2bf(v.x); b.y = (short)f2bf(v.y);
    b.z = (short)f2bf(v.z); b.w = (short)f2bf(v.w);
    *(short4*)&xb[(size_t)i * 4] = b;
  }
}

// W [K][128] f32 -> Wt [128][K] bf16
__global__ void k_prepW(const float* __restrict__ W, unsigned short* __restrict__ Wt,
                        int K) {
  const int idx = blockIdx.x * blockDim.x + threadIdx.x;
  if (idx < K * EMBD) {
    const int k = idx >> 7, n = idx & 127;
    Wt[(size_t)n * K + k] = f2bf(W[(size_t)k * EMBD + n]);
  }
}

// ea f32 [E][32] -> bf16
__global__ void k_prepea(const float* __restrict__ ea,
                         unsigned short* __restrict__ eab) {
  const int tot = EE * 32 / 8;
  for (int i = blockIdx.x * blockDim.x + threadIdx.x; i < tot;
       i += gridDim.x * blockDim.x) {
    const float4 a = ((const float4*)ea)[i * 2];
    const float4 b = ((const float4*)ea)[i * 2 + 1];
    union { unsigned short u[8]; uint4 v; } o;
    o.u[0] = f2bf(a.x); o.u[1] = f2bf(a.y); o.u[2] = f2bf(a.z); o.u[3] = f2bf(a.w);
    o.u[4] = f2bf(b.x); o.u[5] = f2bf(b.y); o.u[6] = f2bf(b.z); o.u[7] = f2bf(b.w);
    ((uint4*)eab)[i] = o.v;
  }
}

// ---------------- PASS0 merged: both phases, CSR order, XCD-chunk swizzle ------
// lst is CSR-ordered, so tiles map to contiguous i-node windows. Phase-local
// block bl starts at tile ((bl&7)<<6)|(bl>>3): each XCD works a contiguous
// ~64-tile window at any time -> its sorted i-rows (~130KB) stay L2-resident.
// NOTE: index-only prefetch. Holding DATA regs across the MFMA phase spills
// (compiler pins ~112 VGPR and spills staging to scratch: r5/r6/r9/r15).

template <int EAB>
__global__ __launch_bounds__(256, 1) void k_pass0m(
    const unsigned short* __restrict__ xb,
    const int* __restrict__ l0, const int* __restrict__ i0,
    const int* __restrict__ j0, const unsigned short* __restrict__ W0,
    float* __restrict__ st0, unsigned short* __restrict__ Y0,
    const int* __restrict__ l1, const int* __restrict__ i1,
    const int* __restrict__ j1, const unsigned short* __restrict__ W1,
    float* __restrict__ st1, unsigned short* __restrict__ Y1,
    const float* __restrict__ ea, const unsigned short* __restrict__ eab,
    const int nb0) {
  __shared__ __align__(16) unsigned short Ab[64 * SAE];
  __shared__ float red[256];
  const int phase = (blockIdx.x >= nb0) ? 1 : 0;
  const int* __restrict__ lst = phase ? l1 : l0;
  const int* __restrict__ idx_i = phase ? i1 : i0;
  const int* __restrict__ idx_j = phase ? j1 : j0;
  const unsigned short* __restrict__ W1t = phase ? W1 : W0;
  float* __restrict__ stat = phase ? st1 : st0;
  unsigned short* __restrict__ Y = phase ? Y1 : Y0;
  const int stride = phase ? ((int)gridDim.x - nb0) : nb0;
  const int bl = blockIdx.x - phase * nb0;
  const int t = threadIdx.x;
  const int lane = t & 63, w = t >> 6, m = lane & 15, kg = lane >> 4;
  const int r = t >> 2, sub = t & 3;
  const int n0 = w * 32 + m, n1 = n0 + 16;
  bf16x8 B0[9], B1[9];
#pragma unroll
  for (int ks = 0; ks < 9; ++ks) {
    B0[ks] = *(const bf16x8*)&W1t[(size_t)n0 * KIN + ks * 32 + kg * 8];
    B1[ks] = *(const bf16x8*)&W1t[(size_t)n1 * KIN + ks * 32 + kg * 8];
  }
  float s0 = 0.f, s1 = 0.f, q0 = 0.f, q1 = 0.f;
  // XCD-chunk swizzle: bijective on [0,512) when stride==512, else identity
  int tile = (stride == 512) ? (((bl & 7) << 6) | (bl >> 3)) : bl;
  int enext = lst[tile * 64 + r];
  int inext = idx_i[enext];
  int jnext = idx_j[enext];
  while (tile < NT_E) {
    const int ecur = enext, icur = inext, jcur = jnext;
    __syncthreads();  // Ab free (prev copy-out done)
    {
      const uint4* xi = (const uint4*)(xb + (size_t)icur * EMBD);
      const uint4* xj = (const uint4*)(xb + (size_t)jcur * EMBD);
      unsigned short* rowp = &Ab[r * SAE];
#pragma unroll
      for (int qq = 0; qq < 8; ++qq) {
        const int c = sub + qq * 4;
        const uint4 v = (c < 16) ? xi[c] : xj[c - 16];
        *(uint4*)&rowp[physch(c, r) * 8] = v;
      }
      uint4 ev;
      if (EAB) {
        ev = *(const uint4*)&eab[(size_t)ecur * 32 + sub * 8];
      } else {
        const float4 e0 = *(const float4*)&ea[(size_t)ecur * 32 + sub * 8];
        const float4 e1 = *(const float4*)&ea[(size_t)ecur * 32 + sub * 8 + 4];
        union { unsigned short u[8]; uint4 v4; } o;
        o.u[0] = f2bf(e0.x); o.u[1] = f2bf(e0.y); o.u[2] = f2bf(e0.z);
        o.u[3] = f2bf(e0.w); o.u[4] = f2bf(e1.x); o.u[5] = f2bf(e1.y);
        o.u[6] = f2bf(e1.z); o.u[7] = f2bf(e1.w);
        ev = o.v4;
      }
      *(uint4*)&rowp[(32 + sub) * 8] = ev;
    }
    __syncthreads();
    const int next = tile + stride;
    if (next < NT_E) {  // idx-only prefetch (3 VGPRs)
      enext = lst[next * 64 + r];
      inext = idx_i[enext];
      jnext = idx_j[enext];
    }
    const f32x4 zz = {0.f, 0.f, 0.f, 0.f};
    f32x4 acc[4][2] = {{zz, zz}, {zz, zz}, {zz, zz}, {zz, zz}};
#pragma unroll
    for (int ks = 0; ks < 9; ++ks) {
      const int aoff = physch(ks * 4 + kg, m) * 8;
#pragma unroll
      for (int mt = 0; mt < 4; ++mt) {
        const bf16x8 a = *(const bf16x8*)&Ab[(mt * 16 + m) * SAE + aoff];
        acc[mt][0] = MFMA16(a, B0[ks], acc[mt][0]);
        acc[mt][1] = MFMA16(a, B1[ks], acc[mt][1]);
      }
    }
#pragma unroll
    for (int mt = 0; mt < 4; ++mt)
#pragma unroll
      for (int r2 = 0; r2 < 4; ++r2) {
        const float v0 = acc[mt][0][r2], v1 = acc[mt][1][r2];
        s0 += v0; q0 += v0 * v0;
        s1 += v1; q1 += v1 * v1;
      }
    __syncthreads();  // all waves done reading Ab
#pragma unroll
    for (int nt = 0; nt < 2; ++nt) {
      const int c = w * 32 + nt * 16 + m;
      const int cc = c >> 3, cl = c & 7;
#pragma unroll
      for (int mt = 0; mt < 4; ++mt)
#pragma unroll
        for (int r2 = 0; r2 < 4; ++r2) {
          const int rw = mt * 16 + kg * 4 + r2;
          Ab[rw * SAE + physch(cc, rw) * 8 + cl] = f2bf(acc[mt][nt][r2]);
        }
    }
    __syncthreads();
    // coalesced writeout: 4 insts x 1KB contiguous per wave (CSR-position order)
    unsigned short* Yt = Y + (size_t)tile * 64 * EMBD;
#pragma unroll
    for (int i = 0; i < 4; ++i) {
      const int g = i * 2048 + t * 8;
      const int row = g >> 7, ch = (g >> 3) & 15;
      *(uint4*)&Yt[g] = *(const uint4*)&Ab[row * SAE + physch(ch, row) * 8];
    }
    tile = next;
  }
  s0 += __shfl_xor(s0, 16); s0 += __shfl_xor(s0, 32);
  q0 += __shfl_xor(q0, 16); q0 += __shfl_xor(q0, 32);
  s1 += __shfl_xor(s1, 16); s1 += __shfl_xor(s1, 32);
  q1 += __shfl_xor(q1, 16); q1 += __shfl_xor(q1, 32);
  if (kg == 0) {
    const int c0 = w * 32 + m, c1 = c0 + 16;
    red[c0] = s0; red[128 + c0] = q0;
    red[c1] = s1; red[128 + c1] = q1;
  }
  __syncthreads();
  if (t < 128) {
    atomicAdd(&stat[t], red[t]);
    atomicAdd(&stat[128 + t], red[128 + t]);
  }
}

// ---------------- PASS1 body: BN1+ReLU -> GEMM2 -> stats2 + Y2 over Y1 ----------

__device__ __forceinline__ void pass1_body(
    const unsigned short* __restrict__ W2t, float* __restrict__ stat,
    unsigned short* __restrict__ Y, int tile, const int stride) {
  __shared__ __align__(16) unsigned short Ab[64 * SA1];
  __shared__ float red[256];
  const int t = threadIdx.x;
  const int lane = t & 63, w = t >> 6, m = lane & 15, kg = lane >> 4;
  const int n0 = w * 32 + m, n1 = n0 + 16;
  const int ch = t & 15;
  bf16x8 B0[4], B1[4];
#pragma unroll
  for (int ks = 0; ks < 4; ++ks) {
    B0[ks] = *(const bf16x8*)&W2t[(size_t)n0 * EMBD + ks * 32 + kg * 8];
    B1[ks] = *(const bf16x8*)&W2t[(size_t)n1 * EMBD + ks * 32 + kg * 8];
  }
  float scr[8], shr[8];
#pragma unroll
  for (int h = 0; h < 8; ++h) {
    scr[h] = stat[256 + ch * 8 + h];
    shr[h] = stat[384 + ch * 8 + h];
  }
  float s0 = 0.f, s1 = 0.f, q0 = 0.f, q1 = 0.f;
  uint4 yreg[4];
  {
    const unsigned short* Yt = Y + (size_t)tile * 64 * EMBD;
#pragma unroll
    for (int i = 0; i < 4; ++i)
      yreg[i] = *(const uint4*)&Yt[i * 2048 + t * 8];
  }
  while (tile < NT_E) {
    __syncthreads();
#pragma unroll
    for (int i = 0; i < 4; ++i) {
      const int row = i * 16 + (t >> 4);
      const unsigned int* pv = (const unsigned int*)&yreg[i];
      union { unsigned short u[8]; uint4 v; } o;
#pragma unroll
      for (int h = 0; h < 4; ++h) {
        const unsigned int pw = pv[h];
        const float f0 = __uint_as_float(pw << 16);
        const float f1 = __uint_as_float(pw & 0xffff0000u);
        o.u[h * 2] = f2bf(fmaxf(fmaf(f0, scr[h * 2], shr[h * 2]), 0.f));
        o.u[h * 2 + 1] = f2bf(fmaxf(fmaf(f1, scr[h * 2 + 1], shr[h * 2 + 1]), 0.f));
      }
      *(uint4*)&Ab[row * SA1 + physch(ch, row) * 8] = o.v;
    }
    __syncthreads();
    const int next = tile + stride;
    if (next < NT_E) {
      const unsigned short* Yt = Y + (size_t)next * 64 * EMBD;
#pragma unroll
      for (int i = 0; i < 4; ++i)
        yreg[i] = *(const uint4*)&Yt[i * 2048 + t * 8];
    }
    const f32x4 zz = {0.f, 0.f, 0.f, 0.f};
    f32x4 acc[4][2] = {{zz, zz}, {zz, zz}, {zz, zz}, {zz, zz}};
#pragma unroll
    for (int ks = 0; ks < 4; ++ks) {
      const int aoff = physch(ks * 4 + kg, m) * 8;
#pragma unroll
      for (int mt = 0; mt < 4; ++mt) {
        const bf16x8 a = *(const bf16x8*)&Ab[(mt * 16 + m) * SA1 + aoff];
        acc[mt][0] = MFMA16(a, B0[ks], acc[mt][0]);
        acc[mt][1] = MFMA16(a, B1[ks], acc[mt][1]);
      }
    }
#pragma unroll
    for (int mt = 0; mt < 4; ++mt)
#pragma unroll
      for (int r2 = 0; r2 < 4; ++r2) {
        const float v0 = acc[mt][0][r2], v1 = acc[mt][1][r2];
        s0 += v0; q0 += v0 * v0;
        s1 += v1; q1 += v1 * v1;
      }
    __syncthreads();
#pragma unroll
    for (int nt = 0; nt < 2; ++nt) {
      const int c = w * 32 + nt * 16 + m;
      const int cc = c >> 3, cl = c & 7;
#pragma unroll
      for (int mt = 0; mt < 4; ++mt)
#pragma unroll
        for (int r2 = 0; r2 < 4; ++r2) {
          const int rw = mt * 16 + kg * 4 + r2;
          Ab[rw * SA1 + physch(cc, rw) * 8 + cl] = f2bf(acc[mt][nt][r2]);
        }
    }
    __syncthreads();
    unsigned short* Yo = Y + (size_t)tile * 64 * EMBD;
#pragma unroll
    for (int i = 0; i < 4; ++i) {
      const int g = i * 2048 + t * 8;
      const int row = g >> 7, c2 = (g >> 3) & 15;
      *(uint4*)&Yo[g] = *(const uint4*)&Ab[row * SA1 + physch(c2, row) * 8];
    }
    tile = next;
  }
  s0 += __shfl_xor(s0, 16); s0 += __shfl_xor(s0, 32);
  q0 += __shfl_xor(q0, 16); q0 += __shfl_xor(q0, 32);
  s1 += __shfl_xor(s1, 16); s1 += __shfl_xor(s1, 32);
  q1 += __shfl_xor(q1, 16); q1 += __shfl_xor(q1, 32);
  if (kg == 0) {
    const int c0 = w * 32 + m, c1 = c0 + 16;
    red[c0] = s0; red[128 + c0] = q0;
    red[c1] = s1; red[128 + c1] = q1;
  }
  __syncthreads();
  if (t < 128) {
    atomicAdd(&stat[512 + t], red[t]);
    atomicAdd(&stat[640 + t], red[128 + t]);
  }
}

__global__ __launch_bounds__(256, 3) void k_pass1(
    const unsigned short* __restrict__ W2t, float* __restrict__ stat,
    unsigned short* __restrict__ Y) {
  pass1_body(W2t, stat, Y, blockIdx.x, G1);
}

__global__ __launch_bounds__(256, 3) void k_pass1m(
    const unsigned short* __restrict__ Wp, const unsigned short* __restrict__ Wc,
    float* __restrict__ statP, float* __restrict__ statC,
    unsigned short* __restrict__ Yp, unsigned short* __restrict__ Yc) {
  const int phase = (blockIdx.x >= G1) ? 1 : 0;
  const unsigned short* W2t = phase ? Wc : Wp;
  float* stat = phase ? statC : statP;
  unsigned short* Y = phase ? Yc : Yp;
  pass1_body(W2t, stat, Y, blockIdx.x - phase * G1, G1);
}

// ---------------- PASS2 merged: Y in CSR order -> SEQUENTIAL reads ------------

__global__ __launch_bounds__(256) void k_aggm(
    const unsigned short* __restrict__ Yp, const unsigned short* __restrict__ Yc,
    const int* __restrict__ offp, const int* __restrict__ offc,
    const float* __restrict__ statP, const float* __restrict__ statC,
    const float* __restrict__ dinvp, const float* __restrict__ dinvc,
    float* __restrict__ agg) {
  const int n = blockIdx.x * 4 + (threadIdx.x >> 6);
  const int lane = threadIdx.x & 63;
  if (n >= NN) return;
  float r0, r1;
  {
    const int o0 = offp[n], o1 = offp[n + 1];
    const float sc0 = statP[768 + 2 * lane], sc1 = statP[768 + 2 * lane + 1];
    const float sh0 = statP[896 + 2 * lane], sh1 = statP[896 + 2 * lane + 1];
    float a0 = 0.f, a1 = 0.f;
    for (int o = o0; o < o1; ++o) {
      const unsigned int pw = ((const unsigned int*)(Yp + (size_t)o * EMBD))[lane];
      a0 += fmaxf(fmaf(__uint_as_float(pw << 16), sc0, sh0), 0.f);
      a1 += fmaxf(fmaf(__uint_as_float(pw & 0xffff0000u), sc1, sh1), 0.f);
    }
    const float d = dinvp[n];
    r0 = a0 * d;
    r1 = a1 * d;
  }
  {
    const int o0 = offc[n], o1 = offc[n + 1];
    const float sc0 = statC[768 + 2 * lane], sc1 = statC[768 + 2 * lane + 1];
    const float sh0 = statC[896 + 2 * lane], sh1 = statC[896 + 2 * lane + 1];
    float a0 = 0.f, a1 = 0.f;
    for (int o = o0; o < o1; ++o) {
      const unsigned int pw = ((const unsigned int*)(Yc + (size_t)o * EMBD))[lane];
      a0 += fmaxf(fmaf(__uint_as_float(pw << 16), sc0, sh0), 0.f);
      a1 += fmaxf(fmaf(__uint_as_float(pw & 0xffff0000u), sc1, sh1), 0.f);
    }
    const float d = dinvc[n];
    r0 += a0 * d;
    r1 += a1 * d;
  }
  float2 out;
  out.x = r0;
  out.y = r1;
  ((float2*)(agg + (size_t)n * EMBD))[lane] = out;
}

template <int ADD>
__global__ __launch_bounds__(256) void k_agg2(
    const unsigned short* __restrict__ Y2, const int* __restrict__ off,
    const float* __restrict__ stat, const float* __restrict__ dinv,
    float* __restrict__ agg) {
  const int n = blockIdx.x * 4 + (threadIdx.x >> 6);
  const int lane = threadIdx.x & 63;
  if (n >= NN) return;
  const int o0 = off[n], o1 = off[n + 1];
  const float sc0 = stat[768 + 2 * lane], sc1 = stat[768 + 2 * lane + 1];
  const float sh0 = stat[896 + 2 * lane], sh1 = stat[896 + 2 * lane + 1];
  float a0 = 0.f, a1 = 0.f;
  for (int o = o0; o < o1; ++o) {
    const unsigned int pw = ((const unsigned int*)(Y2 + (size_t)o * EMBD))[lane];
    a0 += fmaxf(fmaf(__uint_as_float(pw << 16), sc0, sh0), 0.f);
    a1 += fmaxf(fmaf(__uint_as_float(pw & 0xffff0000u), sc1, sh1), 0.f);
  }
  const float d = dinv[n];
  float2 out;
  if (ADD) {
    const float2 prev = ((const float2*)(agg + (size_t)n * EMBD))[lane];
    out.x = prev.x + a0 * d;
    out.y = prev.y + a1 * d;
  } else {
    out.x = a0 * d;
    out.y = a1 * d;
  }
  ((float2*)(agg + (size_t)n * EMBD))[lane] = out;
}

// ---------------- node update GEMM ----------------

template <int NK, bool SWZ>
__device__ __forceinline__ void gemm_g(const unsigned short* Ab, const int sa,
                                       const unsigned short* __restrict__ Wt,
                                       const int K, const int m, const int kg,
                                       const int w, f32x4 acc[4][2]) {
  const int n0 = w * 32 + m, n1 = n0 + 16;
#pragma unroll
  for (int ks = 0; ks < NK; ++ks) {
    const int koff = ks * 32 + kg * 8;
    const int aoff = SWZ ? physch(koff >> 3, m) * 8 : koff;
    const bf16x8 b0 = *(const bf16x8*)&Wt[(size_t)n0 * K + koff];
    const bf16x8 b1 = *(const bf16x8*)&Wt[(size_t)n1 * K + koff];
#pragma unroll
    for (int mt = 0; mt < 4; ++mt) {
      const bf16x8 a = *(const bf16x8*)&Ab[(mt * 16 + m) * sa + aoff];
      acc[mt][0] = MFMA16(a, b0, acc[mt][0]);
      acc[mt][1] = MFMA16(a, b1, acc[mt][1]);
    }
  }
}

__device__ __forceinline__ void stats_epi64(const f32x4 acc[4][2], float* red,
                                            float* __restrict__ statg, const int t,
                                            const int m, const int kg, const int w) {
#pragma unroll
  for (int nt = 0; nt < 2; ++nt) {
    float s = 0.f, q = 0.f;
#pragma unroll
    for (int mt = 0; mt < 4; ++mt)
#pragma unroll
      for (int r = 0; r < 4; ++r) {
        const float v = acc[mt][nt][r];
        s += v;
        q += v * v;
      }
    s += __shfl_xor(s, 16); s += __shfl_xor(s, 32);
    q += __shfl_xor(q, 16); q += __shfl_xor(q, 32);
    if (kg == 0) {
      const int c = w * 32 + nt * 16 + m;
      red[c] = s;
      red[128 + c] = q;
    }
  }
  __syncthreads();
  if (t < 128) {
    atomicAdd(&statg[t], red[t]);
    atomicAdd(&statg[128 + t], red[128 + t]);
  }
}

__global__ __launch_bounds__(256) void k_node(
    const float* __restrict__ nd, float* __restrict__ ag,
    const unsigned short* __restrict__ Wt, float* __restrict__ stat) {
  __shared__ __align__(16) unsigned short Ab[64 * SA1];
  __shared__ float red[256];
  const int t = threadIdx.x;
  const int n0 = blockIdx.x * 64;
  {
    const int r = t >> 2, sub = t & 3;
    const int row = n0 + r;
    unsigned short* drow = &Ab[r * SA1];
#pragma unroll
    for (int q = 0; q < 8; ++q) {
      const int c4 = sub + q * 4;
      float4 va;
      if (row < NN) {
        va = ((const float4*)(nd + (size_t)row * EMBD))[c4];
        const float4 vb = ((const float4*)(ag + (size_t)row * EMBD))[c4];
        va.x += vb.x; va.y += vb.y; va.z += vb.z; va.w += vb.w;
      } else {
        va.x = va.y = va.z = va.w = 0.f;
      }
      short4 b;
      b.x = (short)f2bf(va.x); b.y = (short)f2bf(va.y);
      b.z = (short)f2bf(va.z); b.w = (short)f2bf(va.w);
      *(short4*)&drow[c4 * 4] = b;
    }
  }
  __syncthreads();
  const int lane = t & 63, w = t >> 6, m = lane & 15, kg = lane >> 4;
  const f32x4 zz = {0.f, 0.f, 0.f, 0.f};
  f32x4 acc[4][2] = {{zz, zz}, {zz, zz}, {zz, zz}, {zz, zz}};
  gemm_g<4, false>(Ab, SA1, Wt, EMBD, m, kg, w, acc);
#pragma unroll
  for (int nt = 0; nt < 2; ++nt) {
    const int c = w * 32 + nt * 16 + m;
#pragma unroll
    for (int mt = 0; mt < 4; ++mt)
#pragma unroll
      for (int r = 0; r < 4; ++r) {
        const int row = n0 + mt * 16 + kg * 4 + r;
        if (row < NN) ag[(size_t)row * EMBD + c] = acc[mt][nt][r];
      }
  }
  stats_epi64(acc, red, stat, t, m, kg, w);
}

// ---------------- BN finalize / node residual ----------------

__device__ __forceinline__ void finalize_one(float* __restrict__ sb,
                                             const float* __restrict__ g,
                                             const float* __restrict__ be,
                                             float cnt, int c) {
  const float s = sb[c], sq = sb[EMBD + c];
  const float m = s / cnt;
  float v = sq / cnt - m * m;
  v = fmaxf(v, 0.f);
  const float rs = rsqrtf(v + EPSV);
  const float sc = g[c] * rs;
  sb[256 + c] = sc;
  sb[384 + c] = be[c] - m * sc;
  sb[c] = 0.f;
  sb[EMBD + c] = 0.f;
}

__global__ void k_finalize(float* __restrict__ statbase, const float* __restrict__ g,
                           const float* __restrict__ be, float cnt) {
  const int t = threadIdx.x;
  if (t < EMBD) finalize_one(statbase, g, be, cnt, t);
}

__global__ void k_finalize2(float* __restrict__ sA, const float* __restrict__ gA,
                            const float* __restrict__ bA, float* __restrict__ sB,
                            const float* __restrict__ gB, const float* __restrict__ bB,
                            float cnt) {
  const int t = threadIdx.x;
  if (t < EMBD) finalize_one(sA, gA, bA, cnt, t);
  else finalize_one(sB, gB, bB, cnt, t - EMBD);
}

__global__ void k_update(float* __restrict__ nd, unsigned short* __restrict__ xb,
                         const float* __restrict__ Z, const float* __restrict__ stat) {
  const float* sc = stat + 256;
  const float* sh = stat + 384;
  const int total = NN * EMBD / 4;
  for (int i = blockIdx.x * blockDim.x + threadIdx.x; i < total;
       i += gridDim.x * blockDim.x) {
    const int c4 = i & 31;
    const float4 v = ((const float4*)Z)[i];
    const float4 s4 = ((const float4*)sc)[c4];
    const float4 h4 = ((const float4*)sh)[c4];
    float4 nv = ((float4*)nd)[i];
    nv.x += fmaxf(fmaf(v.x, s4.x, h4.x), 0.f);
    nv.y += fmaxf(fmaf(v.y, s4.y, h4.y), 0.f);
    nv.z += fmaxf(fmaf(v.z, s4.z, h4.z), 0.f);
    nv.w += fmaxf(fmaf(v.w, s4.w, h4.w), 0.f);
    ((float4*)nd)[i] = nv;
    short4 b;
    b.x = (short)f2bf(nv.x); b.y = (short)f2bf(nv.y);
    b.z = (short)f2bf(nv.z); b.w = (short)f2bf(nv.w);
    *(short4*)&xb[(size_t)i * 4] = b;
  }
}

// ---------------- launch ----------------

extern "C" void kernel_launch(void* const* d_in, const int* in_sizes, int n_in,
                              void* d_out, int out_size, void* d_ws, size_t ws_size,
                              hipStream_t stream) {
  const float* in_nodes = (const float*)d_in[0];
  const void* edges = d_in[1];
  const float* ea = (const float*)d_in[2];
  const float* fW = (const float*)d_in[3];
  const float* fg = (const float*)d_in[5];
  const float* fbe = (const float*)d_in[6];
  const float* p_[8];
  const float* c_[8];
  for (int i = 0; i < 8; ++i) {
    p_[i] = (const float*)d_in[7 + i];
    c_[i] = (const float*)d_in[15 + i];
  }
  float* nodes = (float*)d_out;

  char* base = (char*)d_ws;
  size_t cur = 0;
  auto take = [&](size_t bytes) -> void* {
    void* p = base + cur;
    cur = (cur + bytes + 255) & ~(size_t)255;
    return p;
  };
  float* agg = (float*)take((size_t)NN * EMBD * 4);
  unsigned short* xb = (unsigned short*)take((size_t)NN * EMBD * 2);
  int* src = (int*)take(EE * 4);
  int* dst = (int*)take(EE * 4);
  int* lstp = (int*)take(EE * 4);
  int* lstc = (int*)take(EE * 4);
  int* offp = (int*)take((NN + 1) * 4);
  int* offc = (int*)take((NN + 1) * 4);
  int* curp = (int*)take(NN * 4);
  int* curc = (int*)take(NN * 4);
  float* dinvp = (float*)take(NN * 4);
  float* dinvc = (float*)take(NN * 4);
  float* stat = (float*)take(2048 * 4);
  int* flag = (int*)take(4);
  unsigned short* pW1t = (unsigned short*)take((size_t)EMBD * KIN * 2);
  unsigned short* pW2t = (unsigned short*)take((size_t)EMBD * EMBD * 2);
  unsigned short* cW1t = (unsigned short*)take((size_t)EMBD * KIN * 2);
  unsigned short* cW2t = (unsigned short*)take((size_t)EMBD * EMBD * 2);
  unsigned short* fWt = (unsigned short*)take((size_t)EMBD * EMBD * 2);
  unsigned short* Y1p = (unsigned short*)take((size_t)EE * EMBD * 2);  // 102.4 MB
  const size_t y_bytes = (size_t)EE * EMBD * 2;
  const bool useM = (cur + y_bytes) <= ws_size;   // merged path needs Y1c
  unsigned short* Y1c = useM ? (unsigned short*)take(y_bytes) : nullptr;
  const size_t eab_bytes = (size_t)EE * 32 * 2;
  const bool useEab = (cur + eab_bytes) <= ws_size;
  unsigned short* eab = useEab ? (unsigned short*)take(eab_bytes) : nullptr;

  k_zeroi<<<64, 256, 0, stream>>>((int*)stat, 2048);
  k_zeroi<<<128, 256, 0, stream>>>(curp, NN);
  k_zeroi<<<128, 256, 0, stream>>>(curc, NN);
  k_detect<<<1, 256, 0, stream>>>((const long long*)edges, flag);
  k_convert<<<1024, 256, 0, stream>>>(edges, flag, src, dst);
  k_count<<<1024, 256, 0, stream>>>(src, dst, curp, curc);
  k_dinv<<<128, 256, 0, stream>>>(curp, curc, dinvp, dinvc);
  k_scan2<<<2, 1024, 0, stream>>>(curp, curc, offp, offc);
  k_copycur<<<128, 256, 0, stream>>>(offp, offc, curp, curc);
  k_scatter<<<1024, 256, 0, stream>>>(src, dst, curp, curc, lstp, lstc);
  k_initnodes<<<2048, 256, 0, stream>>>(in_nodes, nodes, xb);
  k_prepW<<<(KIN * EMBD + 255) / 256, 256, 0, stream>>>(p_[0], pW1t, KIN);
  k_prepW<<<(EMBD * EMBD + 255) / 256, 256, 0, stream>>>(p_[4], pW2t, EMBD);
  k_prepW<<<(KIN * EMBD + 255) / 256, 256, 0, stream>>>(c_[0], cW1t, KIN);
  k_prepW<<<(EMBD * EMBD + 255) / 256, 256, 0, stream>>>(c_[4], cW2t, EMBD);
  k_prepW<<<(EMBD * EMBD + 255) / 256, 256, 0, stream>>>(fW, fWt, EMBD);
  if (useEab) k_prepea<<<2048, 256, 0, stream>>>(ea, eab);

  const int NB = (NN + 63) / 64;  // 782
  float* statP = stat;
  float* statC = stat + 1024;

  for (int it = 0; it < NITERS; ++it) {
    if (useM) {
      if (useEab)
        k_pass0m<1><<<2 * G0P, 256, 0, stream>>>(
            xb, lstp, dst, src, pW1t, statP, Y1p,
            lstc, src, dst, cW1t, statC, Y1c, ea, eab, G0P);
      else
        k_pass0m<0><<<2 * G0P, 256, 0, stream>>>(
            xb, lstp, dst, src, pW1t, statP, Y1p,
            lstc, src, dst, cW1t, statC, Y1c, ea, eab, G0P);
      k_finalize2<<<1, 256, 0, stream>>>(statP, p_[2], p_[3],
                                         statC, c_[2], c_[3], (float)EE);
      k_pass1m<<<2 * G1, 256, 0, stream>>>(pW2t, cW2t, statP, statC, Y1p, Y1c);
      k_finalize2<<<1, 256, 0, stream>>>(statP + 512, p_[6], p_[7],
                                         statC + 512, c_[6], c_[7], (float)EE);
      k_aggm<<<NN / 4, 256, 0, stream>>>(Y1p, Y1c, offp, offc,
                                         statP, statC, dinvp, dinvc, agg);
    } else {
      k_pass0m<0><<<G0P, 256, 0, stream>>>(
          xb, lstp, dst, src, pW1t, statP, Y1p,
          lstp, dst, src, pW1t, statP, Y1p, ea, eab, G0P);
      k_finalize<<<1, 128, 0, stream>>>(statP, p_[2], p_[3], (float)EE);
      k_pass1<<<G1, 256, 0, stream>>>(pW2t, statP, Y1p);
      k_finalize<<<1, 128, 0, stream>>>(statP + 512, p_[6], p_[7], (float)EE);
      k_agg2<0><<<NN / 4, 256, 0, stream>>>(Y1p, offp, statP, dinvp, agg);
      k_pass0m<0><<<G0P, 256, 0, stream>>>(
          xb, lstc, src, dst, cW1t, statP, Y1p,
          lstc, src, dst, cW1t, statP, Y1p, ea, eab, G0P);
      k_finalize<<<1, 128, 0, stream>>>(statP, c_[2], c_[3], (float)EE);
      k_pass1<<<G1, 256, 0, stream>>>(cW2t, statP, Y1p);
      k_finalize<<<1, 128, 0, stream>>>(statP + 512, c_[6], c_[7], (float)EE);
      k_agg2<1><<<NN / 4, 256, 0, stream>>>(Y1p, offc, statP, dinvc, agg);
    }
    // node update
    k_node<<<NB, 256, 0, stream>>>(nodes, agg, fWt, statP);
    k_finalize<<<1, 128, 0, stream>>>(statP, fg, fbe, (float)NN);
    k_update<<<2048, 256, 0, stream>>>(nodes, xb, agg, statP);
  }
}